// Round 1
// 491.221 us; speedup vs baseline: 1.1086x; 1.1086x over previous
//
#include <hip/hip_runtime.h>

// DynamicGraphAttention: B=16, L=256, D=128, F_IN=64, F_OUT=64
// v5: both matmuls moved to v_mfma_f32_16x16x32_f16 (was 100% VALU, MfmaUtil=0).
// One block per (b,l), 4 waves. f16 staging everywhere (better than prior bf16),
// max-shifted softmax so P fits fp16 range exactly. XOR-swizzled LDS tiles so all
// ds_read_b128 fragment loads are <=2-way (free). adj prefetched one K-tile ahead.
constexpr int D_   = 128;
constexpr int FIN  = 64;
constexpr int FOUT = 64;
constexpr float ALPHA = 0.2f;

typedef _Float16 f16x8 __attribute__((ext_vector_type(8)));
typedef float    f32x4 __attribute__((ext_vector_type(4)));

__global__ __launch_bounds__(256, 4) void gat_kernel(
    const float* __restrict__ hg, const int* __restrict__ adjg,
    const float* __restrict__ Wg, const float* __restrict__ ag,
    float* __restrict__ outg)
{
    // sX (16KB): phase A = h f16 [d][64] swz((d&7)<<4); phase B/C = WhT f16 [o][128] swz((o&7)<<4)
    __shared__ __align__(16) unsigned short sX[128 * 64];
    // sPt (8KB): phase A = W^T f16 [o][64] swz((o&7)<<4); phase C = P-tile f16 [i][32] swz((i&3)<<4)
    __shared__ __align__(16) unsigned short sPt[64 * 64];
    __shared__ __align__(16) float sA[2 * FOUT];
    __shared__ float sEi[D_];
    __shared__ __align__(16) float sEj[D_];
    __shared__ float sL[D_];
    __shared__ float sMxW[4];
    // total ~26.7 KB -> LDS allows 6 blocks/CU; VGPR cap (launch_bounds 256,4) -> 4 blocks/CU

    const int tid  = threadIdx.x;
    const int lane = tid & 63;
    const int w    = tid >> 6;      // wave 0..3, owns output rows [w*32, w*32+32)
    const int g    = lane >> 4;     // k-group 0..3
    const int m16  = lane & 15;

    const long bl = blockIdx.x;
    const float* hp   = hg   + bl * (long)(D_ * FIN);
    const int*   adjp = adjg + bl * (long)(D_ * D_);
    float*       outp = outg + bl * (long)(D_ * FOUT);

    char* xb = (char*)sX;
    char* pb = (char*)sPt;

    const int pi  = tid >> 1;           // P-build row
    const int pjb = (tid & 1) << 4;     // 16-j segment within 32-wide tile

    // ---------------- stage: h -> sX f16 swz, W -> sPt transposed f16 swz, a -> sA ----------------
    {
        const float4* h4 = (const float4*)hp;
        #pragma unroll
        for (int k = 0; k < 8; ++k) {
            int idx = tid + 256 * k;          // float4 index in [0,2048)
            float4 v = h4[idx];
            int row = idx >> 4;               // 16 float4 per 64-float row
            int f   = (idx & 15) << 2;
            union { _Float16 h[4]; uint2 u; } cv;
            cv.h[0] = (_Float16)v.x; cv.h[1] = (_Float16)v.y;
            cv.h[2] = (_Float16)v.z; cv.h[3] = (_Float16)v.w;
            int off = (row * 128 + f * 2) ^ ((row & 7) << 4);
            *(uint2*)(xb + off) = cv.u;
        }
        const float4* W4 = (const float4*)Wg;
        #pragma unroll
        for (int k = 0; k < 4; ++k) {
            int idx = tid + 256 * k;          // [0,1024)
            float4 v = W4[idx];
            int f  = idx >> 4;                // W row (F_IN)
            int o0 = (idx & 15) << 2;         // W col (F_OUT)
            float vv[4] = {v.x, v.y, v.z, v.w};
            #pragma unroll
            for (int q = 0; q < 4; ++q) {
                int o = o0 + q;
                int off = (o * 128 + f * 2) ^ ((o & 7) << 4);
                *(_Float16*)(pb + off) = (_Float16)vv[q];
            }
        }
        if (tid < 2 * FOUT) sA[tid] = ag[tid];
    }

    // prefetch adj tile 0 early (latency hides under staging + phase A/B)
    int4 areg[4];
    {
        const int4* ap = (const int4*)(adjp + pi * D_ + pjb);
        #pragma unroll
        for (int q = 0; q < 4; ++q) areg[q] = ap[q];
    }
    __syncthreads();

    // ---------------- phase A: Wh = h @ W via MFMA 16x16x32 f16 ----------------
    f32x4 acc[2][4];
    #pragma unroll
    for (int mt = 0; mt < 2; ++mt)
        #pragma unroll
        for (int nt = 0; nt < 4; ++nt) acc[mt][nt] = (f32x4){0.f, 0.f, 0.f, 0.f};

    #pragma unroll
    for (int kt = 0; kt < 2; ++kt) {
        f16x8 af[2], bf[4];
        #pragma unroll
        for (int mt = 0; mt < 2; ++mt) {
            int row = w * 32 + mt * 16 + m16;
            af[mt] = *(const f16x8*)(xb + ((row * 128 + kt * 64 + g * 16) ^ ((row & 7) << 4)));
        }
        #pragma unroll
        for (int nt = 0; nt < 4; ++nt) {
            int o = nt * 16 + m16;
            bf[nt] = *(const f16x8*)(pb + ((o * 128 + kt * 64 + g * 16) ^ ((o & 7) << 4)));
        }
        #pragma unroll
        for (int mt = 0; mt < 2; ++mt)
            #pragma unroll
            for (int nt = 0; nt < 4; ++nt)
                acc[mt][nt] = __builtin_amdgcn_mfma_f32_16x16x32_f16(af[mt], bf[nt], acc[mt][nt], 0, 0, 0);
    }
    __syncthreads();   // all sX/sPt reads complete before overwrite

    // ---------------- phase B: e_i/e_j via register butterfly; WhT -> sX ----------------
    {
        float a1v[4], a2v[4];
        #pragma unroll
        for (int nt = 0; nt < 4; ++nt) {
            a1v[nt] = sA[nt * 16 + m16];
            a2v[nt] = sA[FOUT + nt * 16 + m16];
        }
        float wmax = -3.0e38f;
        #pragma unroll
        for (int mt = 0; mt < 2; ++mt) {
            #pragma unroll
            for (int r = 0; r < 4; ++r) {
                float ei = 0.f, ej = 0.f;
                #pragma unroll
                for (int nt = 0; nt < 4; ++nt) {
                    float v = acc[mt][nt][r];
                    ei += v * a1v[nt];
                    ej += v * a2v[nt];
                }
                #pragma unroll
                for (int s = 1; s < 16; s <<= 1) {
                    ei += __shfl_xor(ei, s);
                    ej += __shfl_xor(ej, s);
                }
                int row = w * 32 + mt * 16 + g * 4 + r;   // D-frag row (col=lane&15, row=(lane>>4)*4+reg)
                if (m16 == 0) { sEi[row] = ei; sEj[row] = ej; }
                wmax = fmaxf(wmax, ej);
            }
        }
        wmax = fmaxf(wmax, __shfl_xor(wmax, 16));
        wmax = fmaxf(wmax, __shfl_xor(wmax, 32));
        if (lane == 0) sMxW[w] = wmax;

        // write Wh^T f16 into sX: WhT[o][j], 4 consecutive j per (mt,nt) = one 8B write
        #pragma unroll
        for (int mt = 0; mt < 2; ++mt) {
            int j0r = w * 32 + mt * 16 + g * 4;
            #pragma unroll
            for (int nt = 0; nt < 4; ++nt) {
                int o = nt * 16 + m16;
                union { _Float16 h[4]; uint2 u; } cv;
                cv.h[0] = (_Float16)acc[mt][nt][0];
                cv.h[1] = (_Float16)acc[mt][nt][1];
                cv.h[2] = (_Float16)acc[mt][nt][2];
                cv.h[3] = (_Float16)acc[mt][nt][3];
                int off = (o * 256 + j0r * 2) ^ ((o & 7) << 4);
                *(uint2*)(xb + off) = cv.u;
            }
        }
    }
    __syncthreads();

    // ---------------- phase C: P build (f16, max-shifted) + P @ Wh via MFMA ----------------
    #pragma unroll
    for (int mt = 0; mt < 2; ++mt)
        #pragma unroll
        for (int nt = 0; nt < 4; ++nt) acc[mt][nt] = (f32x4){0.f, 0.f, 0.f, 0.f};

    const float ei_pi = sEi[pi];
    const float mxj = fmaxf(fmaxf(sMxW[0], sMxW[1]), fmaxf(sMxW[2], sMxW[3]));
    float mt_ = ei_pi + mxj;
    const float mi = mt_ > 0.f ? mt_ : ALPHA * mt_;   // = max_j leaky(ei+ej) >= any row entry
    float lpt = 0.f;

    for (int jt = 0; jt < 4; ++jt) {
        const int j0 = jt * 32;
        // build this thread's 16 p values (row pi, j = j0+pjb .. +16)
        union { _Float16 h[8]; uint4 u; } ph0, ph1;
        #pragma unroll
        for (int q = 0; q < 4; ++q) {
            int4 av = areg[q];
            int aa[4] = {av.x, av.y, av.z, av.w};
            float4 ej4 = *(const float4*)&sEj[j0 + pjb + q * 4];
            float ejv[4] = {ej4.x, ej4.y, ej4.z, ej4.w};
            #pragma unroll
            for (int kk = 0; kk < 4; ++kk) {
                float e = ei_pi + ejv[kk];
                e = e > 0.f ? e : ALPHA * e;
                float p = (aa[kk] > 0) ? __expf(e - mi) : 0.f;   // in (0,1] -> exact f16 range
                lpt += p;
                _Float16 pv = (_Float16)p;
                if (q < 2) ph0.h[q * 4 + kk] = pv;
                else       ph1.h[(q - 2) * 4 + kk] = pv;
            }
        }
        {
            int base = pi * 64 + pjb * 2;
            *(uint4*)(pb + ((base)      ^ ((pi & 3) << 4))) = ph0.u;
            *(uint4*)(pb + ((base + 16) ^ ((pi & 3) << 4))) = ph1.u;
        }
        if (jt < 3) {
            // prefetch next adj tile (hides under barrier + MFMA + next build)
            const int4* ap = (const int4*)(adjp + pi * D_ + (jt + 1) * 32 + pjb);
            #pragma unroll
            for (int q = 0; q < 4; ++q) areg[q] = ap[q];
        } else {
            lpt += __shfl_xor(lpt, 1);
            if ((tid & 1) == 0) sL[pi] = lpt;   // visible to epilogue after next barrier
        }
        __syncthreads();

        // MFMA: acc += P[:, j0:j0+32] @ Wh[j0:j0+32, :]
        f16x8 pa[2], wb[4];
        #pragma unroll
        for (int mtx = 0; mtx < 2; ++mtx) {
            int i = w * 32 + mtx * 16 + m16;
            pa[mtx] = *(const f16x8*)(pb + ((i * 64 + g * 16) ^ ((i & 3) << 4)));
        }
        #pragma unroll
        for (int nt = 0; nt < 4; ++nt) {
            int o = nt * 16 + m16;
            wb[nt] = *(const f16x8*)(xb + ((o * 256 + j0 * 2 + g * 16) ^ ((o & 7) << 4)));
        }
        #pragma unroll
        for (int mtx = 0; mtx < 2; ++mtx)
            #pragma unroll
            for (int nt = 0; nt < 4; ++nt)
                acc[mtx][nt] = __builtin_amdgcn_mfma_f32_16x16x32_f16(pa[mtx], wb[nt], acc[mtx][nt], 0, 0, 0);

        if (jt < 3) __syncthreads();   // P-tile consumed before next build overwrites
    }

    // ---------------- epilogue: divide by row sum, write out ----------------
    #pragma unroll
    for (int mtx = 0; mtx < 2; ++mtx) {
        #pragma unroll
        for (int r = 0; r < 4; ++r) {
            int row = w * 32 + mtx * 16 + g * 4 + r;
            float inv = 1.0f / sL[row];
            #pragma unroll
            for (int nt = 0; nt < 4; ++nt)
                outp[row * 64 + nt * 16 + m16] = acc[mtx][nt][r] * inv;
        }
    }
}

extern "C" void kernel_launch(void* const* d_in, const int* in_sizes, int n_in,
                              void* d_out, int out_size, void* d_ws, size_t ws_size,
                              hipStream_t stream) {
    const float* h   = (const float*)d_in[0];
    const int*   adj = (const int*)d_in[1];
    const float* W   = (const float*)d_in[2];
    const float* a   = (const float*)d_in[3];
    float*       out = (float*)d_out;
    gat_kernel<<<dim3(16 * 256), dim3(256), 0, stream>>>(h, adj, W, a, out);
}